// Round 2
// baseline (205.825 us; speedup 1.0000x reference)
//
#include <hip/hip_runtime.h>
#include <hip/hip_cooperative_groups.h>

namespace cg = cooperative_groups;

namespace {
constexpr int H = 2048, W = 2048;
constexpr int CELLS = H * W;
constexpr int PAIRS = CELLS / 2;              // 2 adjacent cells per thread-iter
constexpr int FRAME_ELEMS = 800 * 800 * 3;    // 1,920,000 floats
constexpr int NEWPOS_OFF = FRAME_ELEMS;
constexpr int ENERGY_OFF = FRAME_ELEMS + CELLS * 2;
constexpr int NBLK = 1024, NTHR = 256;        // 4 blocks/CU guaranteed by launch_bounds
constexpr int TOT = NBLK * NTHR;              // 262,144 threads
}

// one spring accumulation, reference op order: f += (p - nb) * (-4)   (exact *4, rn add)
__device__ __forceinline__ void spring(float& f0, float& f1,
                                       float px, float py, float nx, float ny) {
    f0 = __fadd_rn(f0, __fmul_rn(__fsub_rn(px, nx), -4.0f));
    f1 = __fadd_rn(f1, __fmul_rn(__fsub_rn(py, ny), -4.0f));
}

// Compute pos + diff for the cell pair (i, jp), (i, jp+1); all wide loads.
// Replicates the reference f32 op order exactly (DIRS: right, down, left, up).
__device__ __forceinline__ void pair_diff(const float4* __restrict__ pos4,
                                          const float2* __restrict__ pos2,
                                          const float4* __restrict__ prev4,
                                          int cp,
                                          float& pa0, float& pa1, float& pb0, float& pb1,
                                          float& da0, float& da1, float& db0, float& db1) {
    const int i = cp >> 10;          // 1024 pairs per row
    const int jp = (cp & 1023) << 1; // even column of cell A
    const float4 s = pos4[cp];
    pa0 = s.x; pa1 = s.y; pb0 = s.z; pb1 = s.w;
    const bool has_u = (i > 0), has_d = (i < H - 1);
    const bool has_l = (jp > 0), has_r = (jp + 2 < W);
    float4 u, d; float2 l, r;
    if (has_u) u = pos4[cp - 1024];
    if (has_d) d = pos4[cp + 1024];
    if (has_l) l = pos2[(i << 11) + jp - 1];
    if (has_r) r = pos2[(i << 11) + jp + 2];

    float fa0 = -9.8f, fa1 = 0.0f, fb0 = -9.8f, fb1 = 0.0f;
    // DIRS order per cell: right, down, left, up (dependency chains per-cell keep this order)
    spring(fa0, fa1, s.x, s.y, s.z, s.w);                 // A right = B (interior of pair)
    if (has_r) spring(fb0, fb1, s.z, s.w, r.x, r.y);      // B right
    if (has_d) { spring(fa0, fa1, s.x, s.y, d.x, d.y);    // A down
                 spring(fb0, fb1, s.z, s.w, d.z, d.w); }  // B down
    if (has_l) spring(fa0, fa1, s.x, s.y, l.x, l.y);      // A left
    spring(fb0, fb1, s.z, s.w, s.x, s.y);                 // B left = A
    if (has_u) { spring(fa0, fa1, s.x, s.y, u.x, u.y);    // A up
                 spring(fb0, fb1, s.z, s.w, u.z, u.w); }  // B up

    // pinned points: force[-1, 0:1024:9] = 0 ; force[0, 0:2048:9] = 0
    const int jb = jp + 1;
    const bool pinA = ((i == H - 1) && (jp < W / 2) && (jp % 9 == 0)) ||
                      ((i == 0) && (jp % 9 == 0));
    const bool pinB = ((i == H - 1) && (jb < W / 2) && (jb % 9 == 0)) ||
                      ((i == 0) && (jb % 9 == 0));
    if (pinA) { fa0 = 0.0f; fa1 = 0.0f; }
    if (pinB) { fb0 = 0.0f; fb1 = 0.0f; }

    const float4 pv = prev4[cp];
    // newraw = (2*pos - prev) + force ; diff = newraw - pos   (2*pos exact)
    const float nra0 = __fadd_rn(__fsub_rn(__fmul_rn(2.0f, s.x), pv.x), fa0);
    const float nra1 = __fadd_rn(__fsub_rn(__fmul_rn(2.0f, s.y), pv.y), fa1);
    const float nrb0 = __fadd_rn(__fsub_rn(__fmul_rn(2.0f, s.z), pv.z), fb0);
    const float nrb1 = __fadd_rn(__fsub_rn(__fmul_rn(2.0f, s.w), pv.w), fb1);
    da0 = __fsub_rn(nra0, pa0);
    da1 = __fsub_rn(nra1, pa1);
    db0 = __fsub_rn(nrb0, pb0);
    db1 = __fsub_rn(nrb1, pb1);
}

__device__ __forceinline__ void emit_cell(float p0, float p1, float d0, float d1,
                                          float scale, float& n0, float& n1,
                                          float* __restrict__ frame) {
    const float s  = __fadd_rn(__fmul_rn(d0, d0), __fmul_rn(d1, d1));
    const float v  = __fsqrt_rn(s);
    const float vel = __fmul_rn(v, scale);
    const float den = fmaxf(v, 1e-12f);
    n0 = __fadd_rn(p0, __fmul_rn(__fdiv_rn(d0, den), vel));
    n1 = __fadd_rn(p1, __fmul_rn(__fdiv_rn(d1, den), vel));
    // x = n1/2048*784+10 ; y = n0/2048*104+690   (/2048 == *2^-11 exact)
    const float x = __fadd_rn(__fmul_rn(__fmul_rn(n1, 4.8828125e-4f), 784.0f), 10.0f);
    const float y = __fadd_rn(__fmul_rn(__fmul_rn(n0, 4.8828125e-4f), 104.0f), 690.0f);
    const int xi = (int)fminf(fmaxf(x, 0.0f), 803.0f);
    const int yi = (int)fminf(fmaxf(y, 0.0f), 803.0f);
    const int px = xi - 2, py = yi - 2;           // crop [2:802, 2:802]
    if ((unsigned)px < 800u && (unsigned)py < 800u)
        frame[(py * 800 + px) * 3 + 1] = 255.0f;  // green channel
}

__global__ __launch_bounds__(NTHR, 4)
void k_cloth(const float2* __restrict__ pos2, const float2* __restrict__ prev2,
             const float* __restrict__ el_in, float* __restrict__ out,
             double* __restrict__ partials) {
    const float4* pos4  = (const float4*)pos2;
    const float4* prev4 = (const float4*)prev2;
    float4* frame4  = (float4*)out;
    float4* newpos4 = (float4*)(out + NEWPOS_OFF);
    const int tid  = threadIdx.x;
    const int gtid = blockIdx.x * NTHR + tid;

    // ---- phase 1a: zero the frame ----
    for (int k = gtid; k < FRAME_ELEMS / 4; k += TOT)
        frame4[k] = make_float4(0.f, 0.f, 0.f, 0.f);

    // ---- phase 1b: per-block f64 energy partial ----
    double acc = 0.0;
    for (int cp = gtid; cp < PAIRS; cp += TOT) {
        float pa0, pa1, pb0, pb1, da0, da1, db0, db1;
        pair_diff(pos4, pos2, prev4, cp, pa0, pa1, pb0, pb1, da0, da1, db0, db1);
        const float sA = __fadd_rn(__fmul_rn(da0, da0), __fmul_rn(da1, da1));
        const float vA = __fsqrt_rn(sA);
        acc += (double)__fmul_rn(vA, vA);
        const float sB = __fadd_rn(__fmul_rn(db0, db0), __fmul_rn(db1, db1));
        const float vB = __fsqrt_rn(sB);
        acc += (double)__fmul_rn(vB, vB);
    }
    __shared__ double sm[NTHR];
    sm[tid] = acc;
    __syncthreads();
    for (int s = NTHR / 2; s > 0; s >>= 1) {
        if (tid < s) sm[tid] += sm[tid + s];
        __syncthreads();
    }
    if (tid == 0) partials[blockIdx.x] = sm[0];
    __threadfence();

    cg::this_grid().sync();

    // ---- phase 2: every block reduces all partials in identical order ----
    double a2 = 0.0;
    for (int k = tid; k < NBLK; k += NTHR) a2 += partials[k];   // fixed order
    sm[tid] = a2;
    __syncthreads();
    for (int s = NTHR / 2; s > 0; s >>= 1) {
        if (tid < s) sm[tid] += sm[tid + s];
        __syncthreads();
    }
    __shared__ float s_scale;
    if (tid == 0) {
        const float energy = (float)sm[0];
        const float el = el_in[0];
        float en = __fmul_rn(fminf(energy, el), 0.99997f);             // min * DECAY
        en = __fadd_rn(__fmul_rn(en, 0.8f), __fmul_rn(energy, 0.2f)); // blend
        s_scale = __fdiv_rn(en, __fadd_rn(energy, 1e-6f));
        if (blockIdx.x == 0)
            out[ENERGY_OFF] = __fadd_rn(__fmul_rn(el, 0.997f), __fmul_rn(en, 0.003f));
    }
    __syncthreads();
    const float scale = s_scale;

    // ---- phase 3: recompute diff, finalize newpos, scatter pixels ----
    for (int cp = gtid; cp < PAIRS; cp += TOT) {
        float pa0, pa1, pb0, pb1, da0, da1, db0, db1;
        pair_diff(pos4, pos2, prev4, cp, pa0, pa1, pb0, pb1, da0, da1, db0, db1);
        float na0, na1, nb0, nb1;
        emit_cell(pa0, pa1, da0, da1, scale, na0, na1, out);
        emit_cell(pb0, pb1, db0, db1, scale, nb0, nb1, out);
        newpos4[cp] = make_float4(na0, na1, nb0, nb1);
    }
}

extern "C" void kernel_launch(void* const* d_in, const int* in_sizes, int n_in,
                              void* d_out, int out_size, void* d_ws, size_t ws_size,
                              hipStream_t stream) {
    const float2* pos  = (const float2*)d_in[0];
    const float2* prev = (const float2*)d_in[1];
    const float*  el   = (const float*)d_in[2];
    float* out = (float*)d_out;
    double* partials = (double*)d_ws;
    void* args[] = { (void*)&pos, (void*)&prev, (void*)&el, (void*)&out, (void*)&partials };
    hipLaunchCooperativeKernel((void*)k_cloth, dim3(NBLK), dim3(NTHR), args, 0, stream);
}

// Round 3
// 51.794 us; speedup vs baseline: 3.9739x; 3.9739x over previous
//
#include <hip/hip_runtime.h>

namespace {
constexpr int H = 2048, W = 2048;
constexpr int CELLS = H * W;
constexpr int PAIRS = CELLS / 2;              // 2 adjacent cells per thread
constexpr int FRAME_ELEMS = 800 * 800 * 3;    // 1,920,000 floats
constexpr int NEWPOS_OFF = FRAME_ELEMS;
constexpr int ENERGY_OFF = FRAME_ELEMS + CELLS * 2;
constexpr int EN_BLOCKS = 2048, NTHR = 256;   // 8 blocks/CU = 32 waves/CU resident
constexpr int EN_TOT = EN_BLOCKS * NTHR;      // 524,288 threads, 4 pairs each
constexpr int EMIT_BLOCKS = PAIRS / NTHR;     // 8192 blocks, 1 pair/thread
}

// one spring accumulation, reference op order: f += (p - nb) * (-4)
__device__ __forceinline__ void spring(float& f0, float& f1,
                                       float px, float py, float nx, float ny) {
    f0 = __fadd_rn(f0, __fmul_rn(__fsub_rn(px, nx), -4.0f));
    f1 = __fadd_rn(f1, __fmul_rn(__fsub_rn(py, ny), -4.0f));
}

// pos + diff for cell pair (i,jp),(i,jp+1). Exact reference f32 op order
// (DIRS per cell: right, down, left, up). Verified R2: absmax 0.0078 (pass).
__device__ __forceinline__ void pair_diff(const float4* __restrict__ pos4,
                                          const float2* __restrict__ pos2,
                                          const float4* __restrict__ prev4,
                                          int cp,
                                          float& pa0, float& pa1, float& pb0, float& pb1,
                                          float& da0, float& da1, float& db0, float& db1) {
    const int i = cp >> 10;          // 1024 pairs per row
    const int jp = (cp & 1023) << 1;
    const float4 s = pos4[cp];
    pa0 = s.x; pa1 = s.y; pb0 = s.z; pb1 = s.w;
    const bool has_u = (i > 0), has_d = (i < H - 1);
    const bool has_l = (jp > 0), has_r = (jp + 2 < W);
    float4 u, d; float2 l, r;
    if (has_u) u = pos4[cp - 1024];
    if (has_d) d = pos4[cp + 1024];
    if (has_l) l = pos2[(i << 11) + jp - 1];
    if (has_r) r = pos2[(i << 11) + jp + 2];

    float fa0 = -9.8f, fa1 = 0.0f, fb0 = -9.8f, fb1 = 0.0f;
    spring(fa0, fa1, s.x, s.y, s.z, s.w);                 // A right = B
    if (has_r) spring(fb0, fb1, s.z, s.w, r.x, r.y);      // B right
    if (has_d) { spring(fa0, fa1, s.x, s.y, d.x, d.y);    // A down
                 spring(fb0, fb1, s.z, s.w, d.z, d.w); }  // B down
    if (has_l) spring(fa0, fa1, s.x, s.y, l.x, l.y);      // A left
    spring(fb0, fb1, s.z, s.w, s.x, s.y);                 // B left = A
    if (has_u) { spring(fa0, fa1, s.x, s.y, u.x, u.y);    // A up
                 spring(fb0, fb1, s.z, s.w, u.z, u.w); }  // B up

    const int jb = jp + 1;
    const bool pinA = ((i == H - 1) && (jp < W / 2) && (jp % 9 == 0)) ||
                      ((i == 0) && (jp % 9 == 0));
    const bool pinB = ((i == H - 1) && (jb < W / 2) && (jb % 9 == 0)) ||
                      ((i == 0) && (jb % 9 == 0));
    if (pinA) { fa0 = 0.0f; fa1 = 0.0f; }
    if (pinB) { fb0 = 0.0f; fb1 = 0.0f; }

    const float4 pv = prev4[cp];
    const float nra0 = __fadd_rn(__fsub_rn(__fmul_rn(2.0f, s.x), pv.x), fa0);
    const float nra1 = __fadd_rn(__fsub_rn(__fmul_rn(2.0f, s.y), pv.y), fa1);
    const float nrb0 = __fadd_rn(__fsub_rn(__fmul_rn(2.0f, s.z), pv.z), fb0);
    const float nrb1 = __fadd_rn(__fsub_rn(__fmul_rn(2.0f, s.w), pv.w), fb1);
    da0 = __fsub_rn(nra0, pa0);
    da1 = __fsub_rn(nra1, pa1);
    db0 = __fsub_rn(nrb0, pb0);
    db1 = __fsub_rn(nrb1, pb1);
}

__global__ __launch_bounds__(NTHR)
void k_energy(const float2* __restrict__ pos2, const float2* __restrict__ prev2,
              double* __restrict__ partials) {
    const float4* pos4  = (const float4*)pos2;
    const float4* prev4 = (const float4*)prev2;
    const int tid = threadIdx.x;
    double acc = 0.0;
    #pragma unroll
    for (int it = 0; it < PAIRS / EN_TOT; ++it) {          // exactly 4 iterations
        const int cp = it * EN_TOT + blockIdx.x * NTHR + tid;
        float pa0, pa1, pb0, pb1, da0, da1, db0, db1;
        pair_diff(pos4, pos2, prev4, cp, pa0, pa1, pb0, pb1, da0, da1, db0, db1);
        const float sA = __fadd_rn(__fmul_rn(da0, da0), __fmul_rn(da1, da1));
        const float vA = __fsqrt_rn(sA);
        acc += (double)__fmul_rn(vA, vA);
        const float sB = __fadd_rn(__fmul_rn(db0, db0), __fmul_rn(db1, db1));
        const float vB = __fsqrt_rn(sB);
        acc += (double)__fmul_rn(vB, vB);
    }
    __shared__ double sm[NTHR];
    sm[tid] = acc;
    __syncthreads();
    for (int s = NTHR / 2; s > 0; s >>= 1) {
        if (tid < s) sm[tid] += sm[tid + s];
        __syncthreads();
    }
    if (tid == 0) partials[blockIdx.x] = sm[0];
}

__global__ void k_finalize(const double* __restrict__ partials,
                           const float* __restrict__ el_in,
                           float* __restrict__ scale_out,
                           float* __restrict__ out_energy) {
    __shared__ double sm[256];
    const int tid = threadIdx.x;
    double acc = 0.0;
    for (int k = tid; k < EN_BLOCKS; k += 256) acc += partials[k];  // fixed order
    sm[tid] = acc;
    __syncthreads();
    for (int s = 128; s > 0; s >>= 1) {
        if (tid < s) sm[tid] += sm[tid + s];
        __syncthreads();
    }
    if (tid == 0) {
        const float energy = (float)sm[0];
        const float el = el_in[0];
        float en = __fmul_rn(fminf(energy, el), 0.99997f);             // min * DECAY
        en = __fadd_rn(__fmul_rn(en, 0.8f), __fmul_rn(energy, 0.2f)); // pp blend
        scale_out[0] = __fdiv_rn(en, __fadd_rn(energy, 1e-6f));
        out_energy[0] = __fadd_rn(__fmul_rn(el, 0.997f), __fmul_rn(en, 0.003f));
    }
}

// newpos for one cell + its pixel index (always computed; frame region check).
__device__ __forceinline__ int cell_new(float p0, float p1, float d0, float d1,
                                        float scale, float& n0, float& n1) {
    const float s  = __fadd_rn(__fmul_rn(d0, d0), __fmul_rn(d1, d1));
    const float v  = __fsqrt_rn(s);
    const float vel = __fmul_rn(v, scale);
    const float den = fmaxf(v, 1e-12f);
    n0 = __fadd_rn(p0, __fmul_rn(__fdiv_rn(d0, den), vel));
    n1 = __fadd_rn(p1, __fmul_rn(__fdiv_rn(d1, den), vel));
    const float x = __fadd_rn(__fmul_rn(__fmul_rn(n1, 4.8828125e-4f), 784.0f), 10.0f);
    const float y = __fadd_rn(__fmul_rn(__fmul_rn(n0, 4.8828125e-4f), 104.0f), 690.0f);
    const int xi = (int)fminf(fmaxf(x, 0.0f), 803.0f);
    const int yi = (int)fminf(fmaxf(y, 0.0f), 803.0f);
    const int px = xi - 2, py = yi - 2;                    // crop [2:802,2:802]
    if ((unsigned)px < 800u && (unsigned)py < 800u) return py * 800 + px;
    return -1;
}

__global__ __launch_bounds__(NTHR)
void k_emit(const float2* __restrict__ pos2, const float2* __restrict__ prev2,
            const float* __restrict__ scale_p, float* __restrict__ out) {
    const float4* pos4  = (const float4*)pos2;
    const float4* prev4 = (const float4*)prev2;
    float4* newpos4 = (float4*)(out + NEWPOS_OFF);
    const int cp = blockIdx.x * NTHR + threadIdx.x;
    const float scale = scale_p[0];
    float pa0, pa1, pb0, pb1, da0, da1, db0, db1;
    pair_diff(pos4, pos2, prev4, cp, pa0, pa1, pb0, pb1, da0, da1, db0, db1);
    float na0, na1, nb0, nb1;
    const int pixA = cell_new(pa0, pa1, da0, da1, scale, na0, na1);
    const int pixB = cell_new(pb0, pb1, db0, db1, scale, nb0, nb1);
    newpos4[cp] = make_float4(na0, na1, nb0, nb1);

    // Wave-level dedup: stored value is constant (green=255), and consecutive
    // lanes cover consecutive cells of one row (block never spans rows:
    // 1024 pairs/row, 256 pairs/block). A pixel is stored by the first slot
    // in the chain ...laneK.A, laneK.B, laneK+1.A, ... where it appears.
    const int lane = threadIdx.x & 63;
    const int prevB = __shfl_up(pixB, 1);                  // lane 0: own value
    const bool storeA = (pixA >= 0) && !(lane > 0 && prevB == pixA);
    const bool storeB = (pixB >= 0) && (pixB != pixA);
    if (storeA) out[pixA * 3 + 1] = 255.0f;
    if (storeB) out[pixB * 3 + 1] = 255.0f;
}

extern "C" void kernel_launch(void* const* d_in, const int* in_sizes, int n_in,
                              void* d_out, int out_size, void* d_ws, size_t ws_size,
                              hipStream_t stream) {
    const float2* pos  = (const float2*)d_in[0];
    const float2* prev = (const float2*)d_in[1];
    const float*  el   = (const float*)d_in[2];
    float* out = (float*)d_out;
    double* partials = (double*)d_ws;
    float*  scale_p  = (float*)((char*)d_ws + EN_BLOCKS * sizeof(double));

    hipMemsetAsync(out, 0, FRAME_ELEMS * sizeof(float), stream);   // frame = 0.0f
    hipLaunchKernelGGL(k_energy, dim3(EN_BLOCKS), dim3(NTHR), 0, stream,
                       pos, prev, partials);
    hipLaunchKernelGGL(k_finalize, dim3(1), dim3(256), 0, stream,
                       partials, el, scale_p, out + ENERGY_OFF);
    hipLaunchKernelGGL(k_emit, dim3(EMIT_BLOCKS), dim3(NTHR), 0, stream,
                       pos, prev, scale_p, out);
}

// Round 4
// 49.591 us; speedup vs baseline: 4.1504x; 1.0444x over previous
//
#include <hip/hip_runtime.h>

namespace {
constexpr int H = 2048, W = 2048;
constexpr int CELLS = H * W;
constexpr int PAIRS = CELLS / 2;              // 2 adjacent cells per thread
constexpr int FRAME_ELEMS = 800 * 800 * 3;    // 1,920,000 floats
constexpr int NEWPOS_OFF = FRAME_ELEMS;
constexpr int ENERGY_OFF = FRAME_ELEMS + CELLS * 2;
constexpr int EN_BLOCKS = 2048, NTHR = 256;   // 8 blocks/CU = 32 waves/CU resident
constexpr int EN_TOT = EN_BLOCKS * NTHR;      // 524,288 threads, 4 pairs each
constexpr int EMIT_BLOCKS = PAIRS / NTHR;     // 8192 blocks, 1 pair/thread
}

// one spring accumulation, reference op order: f += (p - nb) * (-4)
__device__ __forceinline__ void spring(float& f0, float& f1,
                                       float px, float py, float nx, float ny) {
    f0 = __fadd_rn(f0, __fmul_rn(__fsub_rn(px, nx), -4.0f));
    f1 = __fadd_rn(f1, __fmul_rn(__fsub_rn(py, ny), -4.0f));
}

// pos + diff for cell pair (i,jp),(i,jp+1). Exact reference f32 op order
// (DIRS per cell: right, down, left, up). Verified R2/R3: absmax 0.0078 (pass).
__device__ __forceinline__ void pair_diff(const float4* __restrict__ pos4,
                                          const float2* __restrict__ pos2,
                                          const float4* __restrict__ prev4,
                                          int cp,
                                          float& pa0, float& pa1, float& pb0, float& pb1,
                                          float& da0, float& da1, float& db0, float& db1) {
    const int i = cp >> 10;          // 1024 pairs per row
    const int jp = (cp & 1023) << 1;
    const float4 s = pos4[cp];
    pa0 = s.x; pa1 = s.y; pb0 = s.z; pb1 = s.w;
    const bool has_u = (i > 0), has_d = (i < H - 1);
    const bool has_l = (jp > 0), has_r = (jp + 2 < W);
    float4 u, d; float2 l, r;
    if (has_u) u = pos4[cp - 1024];
    if (has_d) d = pos4[cp + 1024];
    if (has_l) l = pos2[(i << 11) + jp - 1];
    if (has_r) r = pos2[(i << 11) + jp + 2];

    float fa0 = -9.8f, fa1 = 0.0f, fb0 = -9.8f, fb1 = 0.0f;
    spring(fa0, fa1, s.x, s.y, s.z, s.w);                 // A right = B
    if (has_r) spring(fb0, fb1, s.z, s.w, r.x, r.y);      // B right
    if (has_d) { spring(fa0, fa1, s.x, s.y, d.x, d.y);    // A down
                 spring(fb0, fb1, s.z, s.w, d.z, d.w); }  // B down
    if (has_l) spring(fa0, fa1, s.x, s.y, l.x, l.y);      // A left
    spring(fb0, fb1, s.z, s.w, s.x, s.y);                 // B left = A
    if (has_u) { spring(fa0, fa1, s.x, s.y, u.x, u.y);    // A up
                 spring(fb0, fb1, s.z, s.w, u.z, u.w); }  // B up

    const int jb = jp + 1;
    const bool pinA = ((i == H - 1) && (jp < W / 2) && (jp % 9 == 0)) ||
                      ((i == 0) && (jp % 9 == 0));
    const bool pinB = ((i == H - 1) && (jb < W / 2) && (jb % 9 == 0)) ||
                      ((i == 0) && (jb % 9 == 0));
    if (pinA) { fa0 = 0.0f; fa1 = 0.0f; }
    if (pinB) { fb0 = 0.0f; fb1 = 0.0f; }

    const float4 pv = prev4[cp];
    const float nra0 = __fadd_rn(__fsub_rn(__fmul_rn(2.0f, s.x), pv.x), fa0);
    const float nra1 = __fadd_rn(__fsub_rn(__fmul_rn(2.0f, s.y), pv.y), fa1);
    const float nrb0 = __fadd_rn(__fsub_rn(__fmul_rn(2.0f, s.z), pv.z), fb0);
    const float nrb1 = __fadd_rn(__fsub_rn(__fmul_rn(2.0f, s.w), pv.w), fb1);
    da0 = __fsub_rn(nra0, pa0);
    da1 = __fsub_rn(nra1, pa1);
    db0 = __fsub_rn(nrb0, pb0);
    db1 = __fsub_rn(nrb1, pb1);
}

// k1: zero the frame (replaces the 39.5us rocclr fill at 195 GB/s) + energy partials
__global__ __launch_bounds__(NTHR)
void k_energy_zero(const float2* __restrict__ pos2, const float2* __restrict__ prev2,
                   float* __restrict__ out, double* __restrict__ partials) {
    const float4* pos4  = (const float4*)pos2;
    const float4* prev4 = (const float4*)prev2;
    float4* frame4 = (float4*)out;
    const int tid  = threadIdx.x;
    const int gtid = blockIdx.x * NTHR + tid;

    if (gtid < FRAME_ELEMS / 4)                           // 480,000 < 524,288
        frame4[gtid] = make_float4(0.f, 0.f, 0.f, 0.f);

    double acc = 0.0;
    #pragma unroll
    for (int it = 0; it < PAIRS / EN_TOT; ++it) {         // exactly 4 iterations
        const int cp = it * EN_TOT + gtid;
        float pa0, pa1, pb0, pb1, da0, da1, db0, db1;
        pair_diff(pos4, pos2, prev4, cp, pa0, pa1, pb0, pb1, da0, da1, db0, db1);
        const float sA = __fadd_rn(__fmul_rn(da0, da0), __fmul_rn(da1, da1));
        const float vA = __fsqrt_rn(sA);
        acc += (double)__fmul_rn(vA, vA);
        const float sB = __fadd_rn(__fmul_rn(db0, db0), __fmul_rn(db1, db1));
        const float vB = __fsqrt_rn(sB);
        acc += (double)__fmul_rn(vB, vB);
    }
    __shared__ double sm[NTHR];
    sm[tid] = acc;
    __syncthreads();
    for (int s = NTHR / 2; s > 0; s >>= 1) {
        if (tid < s) sm[tid] += sm[tid + s];
        __syncthreads();
    }
    if (tid == 0) partials[blockIdx.x] = sm[0];
}

// newpos for one cell + its pixel index (or -1 if outside the cropped frame).
__device__ __forceinline__ int cell_new(float p0, float p1, float d0, float d1,
                                        float scale, float& n0, float& n1) {
    const float s  = __fadd_rn(__fmul_rn(d0, d0), __fmul_rn(d1, d1));
    const float v  = __fsqrt_rn(s);
    const float vel = __fmul_rn(v, scale);
    const float den = fmaxf(v, 1e-12f);
    n0 = __fadd_rn(p0, __fmul_rn(__fdiv_rn(d0, den), vel));
    n1 = __fadd_rn(p1, __fmul_rn(__fdiv_rn(d1, den), vel));
    const float x = __fadd_rn(__fmul_rn(__fmul_rn(n1, 4.8828125e-4f), 784.0f), 10.0f);
    const float y = __fadd_rn(__fmul_rn(__fmul_rn(n0, 4.8828125e-4f), 104.0f), 690.0f);
    const int xi = (int)fminf(fmaxf(x, 0.0f), 803.0f);
    const int yi = (int)fminf(fmaxf(y, 0.0f), 803.0f);
    const int px = xi - 2, py = yi - 2;                   // crop [2:802,2:802]
    if ((unsigned)px < 800u && (unsigned)py < 800u) return py * 800 + px;
    return -1;
}

// k2: every block redundantly reduces partials (fixed order -> bit-identical
// scale), then finalizes newpos + scatters pixels. Removes the 1-block
// finalize dispatch from the critical path.
__global__ __launch_bounds__(NTHR)
void k_emit(const float2* __restrict__ pos2, const float2* __restrict__ prev2,
            const double* __restrict__ partials, const float* __restrict__ el_in,
            float* __restrict__ out) {
    const float4* pos4  = (const float4*)pos2;
    const float4* prev4 = (const float4*)prev2;
    float4* newpos4 = (float4*)(out + NEWPOS_OFF);
    const int tid = threadIdx.x;

    __shared__ double sm[NTHR];
    double acc = 0.0;
    #pragma unroll
    for (int k = 0; k < EN_BLOCKS / NTHR; ++k)            // 8 loads, fixed order
        acc += partials[k * NTHR + tid];
    // NOTE: this order (k*NTHR+tid) must stay identical across all blocks only;
    // it defines the reduction tree deterministically.
    sm[tid] = acc;
    __syncthreads();
    for (int s = NTHR / 2; s > 0; s >>= 1) {
        if (tid < s) sm[tid] += sm[tid + s];
        __syncthreads();
    }
    __shared__ float s_scale;
    if (tid == 0) {
        const float energy = (float)sm[0];
        const float el = el_in[0];
        float en = __fmul_rn(fminf(energy, el), 0.99997f);             // min * DECAY
        en = __fadd_rn(__fmul_rn(en, 0.8f), __fmul_rn(energy, 0.2f)); // pp blend
        s_scale = __fdiv_rn(en, __fadd_rn(energy, 1e-6f));
        if (blockIdx.x == 0)
            out[ENERGY_OFF] = __fadd_rn(__fmul_rn(el, 0.997f), __fmul_rn(en, 0.003f));
    }
    __syncthreads();
    const float scale = s_scale;

    const int cp = blockIdx.x * NTHR + tid;
    float pa0, pa1, pb0, pb1, da0, da1, db0, db1;
    pair_diff(pos4, pos2, prev4, cp, pa0, pa1, pb0, pb1, da0, da1, db0, db1);
    float na0, na1, nb0, nb1;
    const int pixA = cell_new(pa0, pa1, da0, da1, scale, na0, na1);
    const int pixB = cell_new(pb0, pb1, db0, db1, scale, nb0, nb1);
    newpos4[cp] = make_float4(na0, na1, nb0, nb1);

    // Wave-level dedup (value is constant 255; block never spans rows):
    // first slot in the chain ...laneK.A, laneK.B, laneK+1.A... stores.
    const int lane = tid & 63;
    const int prevB = __shfl_up(pixB, 1);                 // lane 0: own value
    const bool storeA = (pixA >= 0) && !(lane > 0 && prevB == pixA);
    const bool storeB = (pixB >= 0) && (pixB != pixA);
    if (storeA) out[pixA * 3 + 1] = 255.0f;
    if (storeB) out[pixB * 3 + 1] = 255.0f;
}

extern "C" void kernel_launch(void* const* d_in, const int* in_sizes, int n_in,
                              void* d_out, int out_size, void* d_ws, size_t ws_size,
                              hipStream_t stream) {
    const float2* pos  = (const float2*)d_in[0];
    const float2* prev = (const float2*)d_in[1];
    const float*  el   = (const float*)d_in[2];
    float* out = (float*)d_out;
    double* partials = (double*)d_ws;

    hipLaunchKernelGGL(k_energy_zero, dim3(EN_BLOCKS), dim3(NTHR), 0, stream,
                       pos, prev, out, partials);
    hipLaunchKernelGGL(k_emit, dim3(EMIT_BLOCKS), dim3(NTHR), 0, stream,
                       pos, prev, partials, el, out);
}

// Round 5
// 45.254 us; speedup vs baseline: 4.5482x; 1.0958x over previous
//
#include <hip/hip_runtime.h>

namespace {
constexpr int H = 2048, W = 2048;
constexpr int CELLS = H * W;
constexpr int PAIRS = CELLS / 2;              // 2 adjacent cells per thread
constexpr int FRAME_ELEMS = 800 * 800 * 3;    // 1,920,000 floats
constexpr int NEWPOS_OFF = FRAME_ELEMS;
constexpr int ENERGY_OFF = FRAME_ELEMS + CELLS * 2;
constexpr int EN_BLOCKS = 2048, NTHR = 256;   // 8 blocks/CU = 32 waves/CU resident
constexpr int EN_TOT = EN_BLOCKS * NTHR;      // 524,288 threads, 4 pairs each
constexpr int EMIT_BLOCKS = PAIRS / NTHR;     // 8192 blocks, 1 pair/thread
}

// one spring accumulation, reference op order: f += (p - nb) * (-4)
__device__ __forceinline__ void spring(float& f0, float& f1,
                                       float px, float py, float nx, float ny) {
    f0 = __fadd_rn(f0, __fmul_rn(__fsub_rn(px, nx), -4.0f));
    f1 = __fadd_rn(f1, __fmul_rn(__fsub_rn(py, ny), -4.0f));
}

// pos + diff for cell pair (i,jp),(i,jp+1). Exact reference f32 op order
// (DIRS per cell: right, down, left, up). Verified R2-R4: absmax 0.0078 (pass).
__device__ __forceinline__ void pair_diff(const float4* __restrict__ pos4,
                                          const float2* __restrict__ pos2,
                                          const float4* __restrict__ prev4,
                                          int cp,
                                          float& pa0, float& pa1, float& pb0, float& pb1,
                                          float& da0, float& da1, float& db0, float& db1) {
    const int i = cp >> 10;          // 1024 pairs per row
    const int jp = (cp & 1023) << 1;
    const float4 s = pos4[cp];
    pa0 = s.x; pa1 = s.y; pb0 = s.z; pb1 = s.w;
    const bool has_u = (i > 0), has_d = (i < H - 1);
    const bool has_l = (jp > 0), has_r = (jp + 2 < W);
    float4 u, d; float2 l, r;
    if (has_u) u = pos4[cp - 1024];
    if (has_d) d = pos4[cp + 1024];
    if (has_l) l = pos2[(i << 11) + jp - 1];
    if (has_r) r = pos2[(i << 11) + jp + 2];

    float fa0 = -9.8f, fa1 = 0.0f, fb0 = -9.8f, fb1 = 0.0f;
    spring(fa0, fa1, s.x, s.y, s.z, s.w);                 // A right = B
    if (has_r) spring(fb0, fb1, s.z, s.w, r.x, r.y);      // B right
    if (has_d) { spring(fa0, fa1, s.x, s.y, d.x, d.y);    // A down
                 spring(fb0, fb1, s.z, s.w, d.z, d.w); }  // B down
    if (has_l) spring(fa0, fa1, s.x, s.y, l.x, l.y);      // A left
    spring(fb0, fb1, s.z, s.w, s.x, s.y);                 // B left = A
    if (has_u) { spring(fa0, fa1, s.x, s.y, u.x, u.y);    // A up
                 spring(fb0, fb1, s.z, s.w, u.z, u.w); }  // B up

    const int jb = jp + 1;
    const bool pinA = ((i == H - 1) && (jp < W / 2) && (jp % 9 == 0)) ||
                      ((i == 0) && (jp % 9 == 0));
    const bool pinB = ((i == H - 1) && (jb < W / 2) && (jb % 9 == 0)) ||
                      ((i == 0) && (jb % 9 == 0));
    if (pinA) { fa0 = 0.0f; fa1 = 0.0f; }
    if (pinB) { fb0 = 0.0f; fb1 = 0.0f; }

    const float4 pv = prev4[cp];
    const float nra0 = __fadd_rn(__fsub_rn(__fmul_rn(2.0f, s.x), pv.x), fa0);
    const float nra1 = __fadd_rn(__fsub_rn(__fmul_rn(2.0f, s.y), pv.y), fa1);
    const float nrb0 = __fadd_rn(__fsub_rn(__fmul_rn(2.0f, s.z), pv.z), fb0);
    const float nrb1 = __fadd_rn(__fsub_rn(__fmul_rn(2.0f, s.w), pv.w), fb1);
    da0 = __fsub_rn(nra0, pa0);
    da1 = __fsub_rn(nra1, pa1);
    db0 = __fsub_rn(nrb0, pb0);
    db1 = __fsub_rn(nrb1, pb1);
}

// k1: frame zeroing fused (1 float4 store/thread; replaces 39.5us rocclr fill)
// + f64 per-block energy partials.
__global__ __launch_bounds__(NTHR)
void k_energy_zero(const float2* __restrict__ pos2, const float2* __restrict__ prev2,
                   float* __restrict__ out, double* __restrict__ partials) {
    const float4* pos4  = (const float4*)pos2;
    const float4* prev4 = (const float4*)prev2;
    float4* frame4 = (float4*)out;
    const int tid  = threadIdx.x;
    const int gtid = blockIdx.x * NTHR + tid;

    if (gtid < FRAME_ELEMS / 4)                           // 480,000 of 524,288
        frame4[gtid] = make_float4(0.f, 0.f, 0.f, 0.f);

    double acc = 0.0;
    #pragma unroll
    for (int it = 0; it < PAIRS / EN_TOT; ++it) {         // exactly 4 iterations
        const int cp = it * EN_TOT + gtid;
        float pa0, pa1, pb0, pb1, da0, da1, db0, db1;
        pair_diff(pos4, pos2, prev4, cp, pa0, pa1, pb0, pb1, da0, da1, db0, db1);
        const float sA = __fadd_rn(__fmul_rn(da0, da0), __fmul_rn(da1, da1));
        const float vA = __fsqrt_rn(sA);
        acc += (double)__fmul_rn(vA, vA);
        const float sB = __fadd_rn(__fmul_rn(db0, db0), __fmul_rn(db1, db1));
        const float vB = __fsqrt_rn(sB);
        acc += (double)__fmul_rn(vB, vB);
    }
    __shared__ double sm[NTHR];
    sm[tid] = acc;
    __syncthreads();
    for (int s = NTHR / 2; s > 0; s >>= 1) {
        if (tid < s) sm[tid] += sm[tid + s];
        __syncthreads();
    }
    if (tid == 0) partials[blockIdx.x] = sm[0];
}

// k2: single tiny block computes scale + new_energy_l. Off the fat-kernel path
// so k_emit blocks start their big loads at wave launch (R4's in-emit reduce
// gated every block behind a 10-barrier prologue -> 49.6us total).
__global__ void k_finalize(const double* __restrict__ partials,
                           const float* __restrict__ el_in,
                           float* __restrict__ scale_out,
                           float* __restrict__ out_energy) {
    __shared__ double sm[256];
    const int tid = threadIdx.x;
    double acc = 0.0;
    #pragma unroll
    for (int k = 0; k < EN_BLOCKS / 256; ++k)             // fixed order
        acc += partials[k * 256 + tid];
    sm[tid] = acc;
    __syncthreads();
    for (int s = 128; s > 0; s >>= 1) {
        if (tid < s) sm[tid] += sm[tid + s];
        __syncthreads();
    }
    if (tid == 0) {
        const float energy = (float)sm[0];
        const float el = el_in[0];
        float en = __fmul_rn(fminf(energy, el), 0.99997f);             // min * DECAY
        en = __fadd_rn(__fmul_rn(en, 0.8f), __fmul_rn(energy, 0.2f)); // pp blend
        scale_out[0] = __fdiv_rn(en, __fadd_rn(energy, 1e-6f));
        out_energy[0] = __fadd_rn(__fmul_rn(el, 0.997f), __fmul_rn(en, 0.003f));
    }
}

// newpos for one cell + its pixel index (or -1 if outside the cropped frame).
__device__ __forceinline__ int cell_new(float p0, float p1, float d0, float d1,
                                        float scale, float& n0, float& n1) {
    const float s  = __fadd_rn(__fmul_rn(d0, d0), __fmul_rn(d1, d1));
    const float v  = __fsqrt_rn(s);
    const float vel = __fmul_rn(v, scale);
    const float den = fmaxf(v, 1e-12f);
    n0 = __fadd_rn(p0, __fmul_rn(__fdiv_rn(d0, den), vel));
    n1 = __fadd_rn(p1, __fmul_rn(__fdiv_rn(d1, den), vel));
    const float x = __fadd_rn(__fmul_rn(__fmul_rn(n1, 4.8828125e-4f), 784.0f), 10.0f);
    const float y = __fadd_rn(__fmul_rn(__fmul_rn(n0, 4.8828125e-4f), 104.0f), 690.0f);
    const int xi = (int)fminf(fmaxf(x, 0.0f), 803.0f);
    const int yi = (int)fminf(fmaxf(y, 0.0f), 803.0f);
    const int px = xi - 2, py = yi - 2;                   // crop [2:802,2:802]
    if ((unsigned)px < 800u && (unsigned)py < 800u) return py * 800 + px;
    return -1;
}

// k3: R3-style emit — reads one scalar scale, no per-block reduce, no barriers.
__global__ __launch_bounds__(NTHR)
void k_emit(const float2* __restrict__ pos2, const float2* __restrict__ prev2,
            const float* __restrict__ scale_p, float* __restrict__ out) {
    const float4* pos4  = (const float4*)pos2;
    const float4* prev4 = (const float4*)prev2;
    float4* newpos4 = (float4*)(out + NEWPOS_OFF);
    const int cp = blockIdx.x * NTHR + threadIdx.x;
    const float scale = scale_p[0];
    float pa0, pa1, pb0, pb1, da0, da1, db0, db1;
    pair_diff(pos4, pos2, prev4, cp, pa0, pa1, pb0, pb1, da0, da1, db0, db1);
    float na0, na1, nb0, nb1;
    const int pixA = cell_new(pa0, pa1, da0, da1, scale, na0, na1);
    const int pixB = cell_new(pb0, pb1, db0, db1, scale, nb0, nb1);
    newpos4[cp] = make_float4(na0, na1, nb0, nb1);

    // Wave-level dedup (value is constant 255; block never spans rows):
    // first slot in the chain ...laneK.A, laneK.B, laneK+1.A... stores.
    const int lane = threadIdx.x & 63;
    const int prevB = __shfl_up(pixB, 1);                 // lane 0: own value
    const bool storeA = (pixA >= 0) && !(lane > 0 && prevB == pixA);
    const bool storeB = (pixB >= 0) && (pixB != pixA);
    if (storeA) out[pixA * 3 + 1] = 255.0f;
    if (storeB) out[pixB * 3 + 1] = 255.0f;
}

extern "C" void kernel_launch(void* const* d_in, const int* in_sizes, int n_in,
                              void* d_out, int out_size, void* d_ws, size_t ws_size,
                              hipStream_t stream) {
    const float2* pos  = (const float2*)d_in[0];
    const float2* prev = (const float2*)d_in[1];
    const float*  el   = (const float*)d_in[2];
    float* out = (float*)d_out;
    double* partials = (double*)d_ws;
    float*  scale_p  = (float*)((char*)d_ws + EN_BLOCKS * sizeof(double));

    hipLaunchKernelGGL(k_energy_zero, dim3(EN_BLOCKS), dim3(NTHR), 0, stream,
                       pos, prev, out, partials);
    hipLaunchKernelGGL(k_finalize, dim3(1), dim3(256), 0, stream,
                       partials, el, scale_p, out + ENERGY_OFF);
    hipLaunchKernelGGL(k_emit, dim3(EMIT_BLOCKS), dim3(NTHR), 0, stream,
                       pos, prev, scale_p, out);
}